// Round 8
// baseline (311.734 us; speedup 1.0000x reference)
//
#include <hip/hip_runtime.h>
#include <hip/hip_bf16.h>

// Problem constants
#define B_ 16
#define L_ 1024
#define H_ 1024
#define N_ 64
// M = B*L = 16384, K = H = 1024, output cols = 2H = 2048 (a|g pairs)
// Chunked SSM: T=64 chunk, 16 chunks/seq.

typedef __bf16 bf16x8 __attribute__((ext_vector_type(8)));
typedef float  f32x4  __attribute__((ext_vector_type(4)));
typedef unsigned short u16x4 __attribute__((ext_vector_type(4)));
typedef unsigned short u16x8 __attribute__((ext_vector_type(8)));

// async global->LDS, 16B per lane; LDS dest is wave-uniform base + lane*16
__device__ __forceinline__ void gll16(const void* g, void* l) {
    __builtin_amdgcn_global_load_lds(
        (const __attribute__((address_space(1))) unsigned int*)g,
        (__attribute__((address_space(3))) unsigned int*)l,
        16, 0, 0);
}

// hardware transpose-read. Semantics (HW-verified round 4):
// lane supplies the address of ITS 64-bit slot; HW forms the 128B-aligned
// window W = addr & ~127, slot i = (addr>>3)&15, and delivers the 4 bf16 at
// bytes W + i*2 + j*32 (j=0..3) — i.e. column i of the window viewed as a
// [4][16] row-major bf16 subtile. Correct usage: addr = subtile_base + lm*8.
__device__ __forceinline__ unsigned long long tr16(unsigned a) {
    unsigned long long d;
    asm volatile("ds_read_b64_tr_b16 %0, %1" : "=v"(d) : "v"(a));
    return d;
}

__device__ __forceinline__ float gelu_tanh(float yv) {
    float u = yv + 0.044715f * yv * yv * yv;
    return 0.5f * yv * (1.0f + tanhf(0.7978845608028654f * u));
}

// Wt row permutation: W col c (c<1024: a-weight h=c; c>=1024: g-weight
// h=c-1024) stored at row r = ((c&1023)>>4)*32 + (c>>10)*16 + (c&15).
// 16-row a-blocks and g-blocks interleave -> 256-row GEMM N-tiles carry
// (a,g) pairs for the same h's, enabling lane-local GLU in gemm_glu.
__device__ __forceinline__ int wt_perm(int c) {
    return (((c & 1023) >> 4) << 5) | (((c >> 10) & 1) << 4) | (c & 15);
}

// ---------------------------------------------------------------------------
// K0 "prep": one kernel, 2176 blocks x 256 threads.
//  [0,1024):    x [B,L,H] f32 -> xTb [B*H, L] bf16 — LDS-staged transpose:
//               coalesced 1KB row reads -> swizzled 32KB LDS tile ->
//               coalesced 128B row writes.
//  [1024,1152): W [1024,2048] f32 -> Wt bf16, rows PERMUTED by wt_perm.
//  [1152,2176): build_tables (Bt/Qt/wT), one h per block (sm[0..2304) only)
// ---------------------------------------------------------------------------
__global__ __launch_bounds__(256) void prep(
        const float* __restrict__ x, const float* __restrict__ log_dt,
        const float* __restrict__ Arl, const float* __restrict__ Aim,
        const float* __restrict__ Cr, const float* __restrict__ Ci,
        const float* __restrict__ W,
        __hip_bfloat16* __restrict__ xTb, __hip_bfloat16* __restrict__ Bt,
        __hip_bfloat16* __restrict__ Qt, float2* __restrict__ wT,
        __hip_bfloat16* __restrict__ Wt) {
    __shared__ char sm[32768];
    int idx = blockIdx.x, t = threadIdx.x;
    int wv = t >> 6, lane = t & 63;

    if (idx < 1152) {
        // ---- transpose (x or W): 64 rows x 256 cols f32 -> bf16 ----
        const float* src;            // input tile base (row 0, col 0)
        size_t in_stride;            // input row stride (floats)
        unsigned short* dstX = 0;    // x-case output tile base
        int k0W = 0, nb0W = 0;       // W-case params
        bool isX = (idx < 1024);
        if (isX) {
            int b = idx >> 6, lt = (idx >> 2) & 15, ht = idx & 3;
            int l0 = lt * 64, hb0 = ht * 256;
            src = x + ((size_t)b * L_ + l0) * H_ + hb0;
            in_stride = H_;
            dstX = (unsigned short*)xTb + ((size_t)b * H_ + hb0) * L_ + l0;
        } else {
            int id2 = idx - 1024;
            int kt = id2 >> 3, ntile = id2 & 7;
            k0W = kt * 64; nb0W = ntile * 256;
            src = W + (size_t)k0W * 2048 + nb0W;
            in_stride = 2048;
        }
        // phase A: row r = j*4+wv, lane covers 4 cols -> 8B swizzled LDS write
#pragma unroll
        for (int j = 0; j < 16; ++j) {
            int r = j * 4 + wv;
            float4 v = *(const float4*)(src + (size_t)r * in_stride + lane * 4);
            __hip_bfloat16 h0 = __float2bfloat16(v.x), h1 = __float2bfloat16(v.y),
                           h2 = __float2bfloat16(v.z), h3 = __float2bfloat16(v.w);
            u16x4 pk;
            pk[0] = *(unsigned short*)&h0; pk[1] = *(unsigned short*)&h1;
            pk[2] = *(unsigned short*)&h2; pk[3] = *(unsigned short*)&h3;
            *(u16x4*)(sm + r * 512 + ((lane * 8) ^ (((r >> 3) & 7) << 4))) = pk;
        }
        __syncthreads();
        // phase B: out row hh = i*32+wv*8+r8, lane's c8 picks 8-col chunk
        {
            int r8l = lane >> 3, c8l = lane & 7;
            int swz = c8l << 4;          // (r>>3)&7 == c8l for r = c8l*8+k
#pragma unroll
            for (int i = 0; i < 8; ++i) {
                int hh = i * 32 + wv * 8 + r8l;
                u16x8 o;
#pragma unroll
                for (int k = 0; k < 8; ++k) {
                    int r = c8l * 8 + k;
                    o[k] = *(unsigned short*)(sm + r * 512 + ((hh * 2) ^ swz));
                }
                if (isX) {
                    *(u16x8*)(dstX + (size_t)hh * L_ + c8l * 8) = o;
                } else {
                    int c = nb0W + hh;
                    int rr = wt_perm(c);
                    *(u16x8*)((unsigned short*)Wt + (size_t)rr * H_ + k0W
                              + c8l * 8) = o;
                }
            }
        }
        return;
    }
    // ---- build_tables: h = idx - 1152 ----
    {
        float* drs  = (float*)sm;            // [64]
        float* dis  = (float*)(sm + 256);    // [64]
        float* c2rs = (float*)(sm + 512);    // [64]
        float* c2is = (float*)(sm + 768);    // [64]
        float (*kp)[64] = (float(*)[64])(sm + 1024);  // [4][64]
        float* kv   = (float*)(sm + 2048);   // [64]
        int h = idx - 1152;

        if (t < 64) {
            int n = t, i = h * 64 + n;
            float dt = expf(log_dt[h]);
            float ar = -expf(Arl[i]), ai = Aim[i];
            float dr = dt * ar, di = dt * ai;
            drs[n] = dr; dis[n] = di;
            float e = expf(dr);
            float wr = e * cosf(di), wi = e * sinf(di);
            float em1r = wr - 1.0f, em1i = wi;
            float Crv = Cr[i], Civ = Ci[i];
            float tr = Crv * em1r - Civ * em1i;
            float ti = Crv * em1i + Civ * em1r;
            float inv = 1.0f / (ar * ar + ai * ai);
            c2rs[n] = 2.0f * (tr * ar + ti * ai) * inv;
            c2is[n] = 2.0f * (ti * ar - tr * ai) * inv;
            // w^64 for the chunk-scan carry
            float jf = 64.0f;
            float er64 = expf(jf * dr);
            float ph64 = jf * di;
            wT[h * 64 + n] = make_float2(er64 * cosf(ph64), er64 * sinf(ph64));
        }
        __syncthreads();
        // kv[j] = sum_n c2r*Re(w^j) - c2i*Im(w^j), partial sums per 16-n part
        {
            int j = t & 63, part = t >> 6;
            float jf = (float)j;
            float s = 0.0f;
            for (int nn = part * 16; nn < part * 16 + 16; ++nn) {
                float er = expf(jf * drs[nn]);
                float ph = jf * dis[nn];
                float wr = er * cosf(ph), wi = er * sinf(ph);
                s += c2rs[nn] * wr - c2is[nn] * wi;
            }
            kp[part][j] = s;
        }
        __syncthreads();
        if (t < 64) kv[t] = kp[0][t] + kp[1][t] + kp[2][t] + kp[3][t];
        __syncthreads();
        // Bt rows 0..63: causal lower-triangular kernel
#pragma unroll
        for (int it = 0; it < 16; ++it) {
            int id3 = it * 256 + t, row = id3 >> 6, col = id3 & 63;
            int d = row - col;
            float v = (d >= 0) ? kv[d] : 0.0f;
            Bt[(size_t)(h * 192 + row) * 64 + col] = __float2bfloat16(v);
        }
        // Bt rows 64..191: w^(63-j) powers, rows 64+2n (Re) / 64+2n+1 (Im)
#pragma unroll
        for (int it = 0; it < 16; ++it) {
            int id3 = it * 256 + t;
            int n = id3 >> 6, j = id3 & 63;
            float jf = (float)(63 - j);
            float er = expf(jf * drs[n]);
            float ph = jf * dis[n];
            float wr = er * cosf(ph), wi = er * sinf(ph);
            Bt[(size_t)(h * 192 + 64 + 2 * n) * 64 + j]     = __float2bfloat16(wr);
            Bt[(size_t)(h * 192 + 64 + 2 * n + 1) * 64 + j] = __float2bfloat16(wi);
        }
        // Qt: row trow, col pair (2n, 2n+1) = (Re, -Im) of c2 * w^(trow+1)
#pragma unroll
        for (int it = 0; it < 16; ++it) {
            int id3 = it * 256 + t;
            int trow = id3 >> 6, n = id3 & 63;
            float jf = (float)(trow + 1);
            float er = expf(jf * drs[n]);
            float ph = jf * dis[n];
            float wr = er * cosf(ph), wi = er * sinf(ph);
            float cR = c2rs[n] * wr - c2is[n] * wi;
            float cI = c2rs[n] * wi + c2is[n] * wr;
            __hip_bfloat16* qp = Qt + (size_t)(h * 64 + trow) * 128 + 2 * n;
            qp[0] = __float2bfloat16(cR);
            qp[1] = __float2bfloat16(-cI);
        }
    }
}

// ---------------------------------------------------------------------------
// K2: fused chunked SSM (M=64 rows = 4 batches, 48K LDS, 3 blocks/CU).
// ---------------------------------------------------------------------------
__global__ __launch_bounds__(256, 3) void chunk_scan(
        const __hip_bfloat16* __restrict__ xTb, const char* __restrict__ Btg,
        const char* __restrict__ Qtg, const float2* __restrict__ wTg,
        const float* __restrict__ Dv, __hip_bfloat16* __restrict__ yTa) {
    __shared__ char lds[49152];
    char* sX = lds;              // [64][128B]
    char* sB = lds + 8192;       // [192][128B]
    char* sS = lds;              // [64 rows][512B] f32, post-GEMM1 overlay
    char* sQ = lds + 32768;      // [64][256B]

    int tid = threadIdx.x, wv = tid >> 6, lane = tid & 63;
    int lm = lane & 15, q = lane >> 4, r8 = lane >> 3, c8 = lane & 7;
    // XCD-aware decode: h = (idx>>5)*8 + (idx&7); member m = (idx>>3)&3
    int idx = blockIdx.x;
    int h  = ((idx >> 5) << 3) | (idx & 7);
    int b0 = ((idx >> 3) & 3) * 4;

    int csrc = c8 ^ r8;
    // ---- stage sB: 24 wave-loads of 8 rows x 128B ----
#pragma unroll
    for (int j = 0; j < 6; ++j) {
        int i = wv * 6 + j;
        gll16(Btg + ((size_t)(h * 192 + i * 8 + r8)) * 128 + csrc * 16,
              sB + i * 1024);
    }
    // ---- stage sQ: 16 wave-loads of 4 rows x 256B ----
    {
        int r4 = lane >> 4, c16 = lane & 15;
#pragma unroll
        for (int j = 0; j < 4; ++j) {
            int i = wv * 4 + j;
            gll16(Qtg + (size_t)(h * 64 + i * 4 + r4) * 256 + (c16 ^ r4) * 16,
                  sQ + i * 1024);
        }
    }
    // ---- stage sX via gll16: 8 groups of 8 rows x 128B, 2 per wave ----
    {
        const char* xb = (const char*)xTb;
#pragma unroll
        for (int j = 0; j < 2; ++j) {
            int i = wv * 2 + j;                      // row group
            int bp = b0 + (i >> 1);                  // batch of this group
            int ch = (i & 1) * 8 + r8;               // chunk index (row&15)
            gll16(xb + ((size_t)(bp * H_ + h)) * 2048 + ch * 128 + csrc * 16,
                  sX + i * 1024);
        }
    }
    __syncthreads();

    // ---- GEMM1: wave rows wv*16+lm, N=192 (12 tiles), K=64 ----
    f32x4 acc[12];
#pragma unroll
    for (int nt = 0; nt < 12; ++nt) acc[nt] = (f32x4){0.f, 0.f, 0.f, 0.f};
#pragma unroll
    for (int kk = 0; kk < 2; ++kk) {
        int clog = kk * 4 + q;
        int m = wv * 16 + lm;
        bf16x8 af = *(const bf16x8*)(sX + m * 128 + ((clog ^ (m & 7)) * 16));
#pragma unroll
        for (int nt = 0; nt < 12; ++nt) {
            int nrow = nt * 16 + lm;
            bf16x8 bf = *(const bf16x8*)(sB + nrow * 128 + ((clog ^ (nrow & 7)) * 16));
            acc[nt] = __builtin_amdgcn_mfma_f32_16x16x32_bf16(
                af, bf, acc[nt], 0, 0, 0);
        }
    }
    __syncthreads();   // everyone done with sX/sB -> sS overlay is safe

    // ---- write Sloc (nt 4..11 -> ri 0..127) into sS f32 swizzled ----
#pragma unroll
    for (int nt = 4; nt < 12; ++nt) {
        int ri = (nt - 4) * 16 + lm;
#pragma unroll
        for (int r = 0; r < 4; ++r) {
            int row = wv * 16 + q * 4 + r;
            *(float*)(sS + row * 512 + (((ri >> 2) ^ (row & 7)) * 16)
                      + (ri & 3) * 4) = acc[nt][r];
        }
    }
    __syncthreads();

    // ---- serial chunk scan: one chain per thread (n = tid&63, bp = wv) ----
    {
        int n = tid & 63, bp = tid >> 6;
        float2 wt = wTg[h * 64 + n];             // w^64
        float sr = 0.0f, si = 0.0f;
#pragma unroll 1
        for (int c = 0; c < 16; ++c) {
            int row = bp * 16 + c;
            char* p = sS + row * 512 + (((n >> 1) ^ (row & 7)) * 16)
                      + (n & 1) * 8;
            float2 loc = *(float2*)p;
            *(float2*)p = make_float2(sr, si);   // S_in before update
            float nr2 = wt.x * sr - wt.y * si + loc.x;
            float ni2 = wt.x * si + wt.y * sr + loc.y;
            sr = nr2; si = ni2;
        }
    }
    __syncthreads();

    // ---- GEMM2: y += S_in[64 x 128] * Qt^T, K=128 (4 k-steps) ----
#pragma unroll
    for (int ks = 0; ks < 4; ++ks) {
        int row = wv * 16 + lm;
        int cf0 = ks * 8 + q * 2;
        f32x4 a0 = *(const f32x4*)(sS + row * 512 + ((cf0 ^ (row & 7)) * 16));
        f32x4 a1 = *(const f32x4*)(sS + row * 512 + (((cf0 + 1) ^ (row & 7)) * 16));
        bf16x8 af;
        af[0] = (__bf16)a0[0]; af[1] = (__bf16)a0[1];
        af[2] = (__bf16)a0[2]; af[3] = (__bf16)a0[3];
        af[4] = (__bf16)a1[0]; af[5] = (__bf16)a1[1];
        af[6] = (__bf16)a1[2]; af[7] = (__bf16)a1[3];
#pragma unroll
        for (int nt = 0; nt < 4; ++nt) {
            int trow = nt * 16 + lm;
            int clog = ks * 4 + q;
            bf16x8 bq = *(const bf16x8*)(sQ + trow * 256 + ((clog ^ (trow & 3)) * 16));
            acc[nt] = __builtin_amdgcn_mfma_f32_16x16x32_bf16(
                af, bq, acc[nt], 0, 0, 0);
        }
    }

    // ---- epilogue: D-skip (bf16 x) + GELU -> yTa ----
    float Dh = Dv[h];
#pragma unroll
    for (int nt = 0; nt < 4; ++nt)
#pragma unroll
        for (int r = 0; r < 4; ++r) {
            int row = wv * 16 + q * 4 + r;
            int seq = (b0 + (row >> 4)) * H_ + h;
            int l   = (row & 15) * 64 + nt * 16 + lm;
            float xv = __bfloat162float(xTb[(size_t)seq * L_ + l]);
            float yv = acc[nt][r] + xv * Dh;
            yTa[(size_t)seq * L_ + l] = __float2bfloat16(gelu_tanh(yv));
        }
}

// ---------------------------------------------------------------------------
// K4: Z = Y @ Wt^T (+b), fused GLU. 256x256 tile, 8 waves (512 thr).
// A from yTa = Y^T via tr16; Wt rows a/g-interleaved by wt_perm so each
// wave's 4 n-tiles are (a,g,a,g) for the same h's -> lane-local GLU.
// LDS 64KB single-buffer: sA@0 32KB subtiled [16 kq][16 msub][4k][16m],
// sB@32KB [256 rows][128B] XOR-swizzled. Per wave per kt: 32 tr16 + 4
// ds_read_b128 per kk, 64 MFMA -> 375B LDS-read/MFMA (was 500).
// ---------------------------------------------------------------------------
__global__ __launch_bounds__(512, 2) void gemm_glu(
        const __hip_bfloat16* __restrict__ Yt, const __hip_bfloat16* __restrict__ Wt,
        const float* __restrict__ bv, float* __restrict__ out) {
    __shared__ char lds[65536];
    char* sA = lds;              // 32KB
    char* sB = lds + 32768;     // 32KB

    int tid = threadIdx.x, wv = tid >> 6, lane = tid & 63;
    int gx = blockIdx.x & 63;
    int mb = gx * 256;
    int nb = (blockIdx.x >> 6) * 256;   // Wt-row base (permuted space)
    int bat = gx >> 2;                  // batch of this M-tile
    int l0 = (gx & 3) * 256;            // sequence-pos base
    int r8 = lane >> 3, c8 = lane & 7, csrc = c8 ^ r8;
    int wm8 = (wv >> 2) * 128;          // wave m-base (2 groups)
    int wn8 = (wv & 3) * 64;            // wave n-base (4 groups)
    int lm = lane & 15, q = lane >> 4;

    // A-staging per-lane decode (issue i: kq4 = i>>1, m-half = i&1):
    // k = kq4*4 + kA, m = (i&1)*128 + mA (+0..7 contiguous)
    int kA = (lane >> 1) & 3;
    int mA = (lane >> 3) * 16 + (lane & 1) * 8;

    const char* Yb = (const char*)Yt;
    const char* Wb = (const char*)Wt;
    unsigned aBase = (unsigned)(size_t)sA;

    f32x4 acc[8][4];
#pragma unroll
    for (int i = 0; i < 8; ++i)
#pragma unroll
        for (int j = 0; j < 4; ++j) acc[i][j] = (f32x4){0.f, 0.f, 0.f, 0.f};

#pragma unroll 1
    for (int kt = 0; kt < 16; ++kt) {
        int k0b = kt * 128;      // byte offset into Wt rows
        __syncthreads();         // readers of previous tile done
        // ---- stage A: 32 issues of 1KB (4 per wave) ----
#pragma unroll
        for (int j = 0; j < 4; ++j) {
            int i = wv * 4 + j;
            int kq4 = i >> 1, mh = i & 1;
            gll16(Yb + ((size_t)(bat * H_ + kt * 64 + kq4 * 4 + kA)) * 2048
                      + (size_t)(l0 + mh * 128 + mA) * 2,
                  sA + i * 1024);
        }
        // ---- stage B: 32 issues of 8 rows x 128B (4 per wave) ----
#pragma unroll
        for (int j = 0; j < 4; ++j) {
            int i = wv * 4 + j;
            gll16(Wb + (size_t)(nb + i * 8 + r8) * 2048 + k0b + csrc * 16,
                  sB + i * 1024);
        }
        __syncthreads();         // stage visible
#pragma unroll
        for (int kk = 0; kk < 2; ++kk) {
            int clog = kk * 4 + q;   // k-octet index for this lane-quad
            // ---- A-fragments: 2 tr16 per mt (k-quads 2clog, 2clog+1) ----
            unsigned long long r0[8], r1[8];
#pragma unroll
            for (int mt = 0; mt < 8; ++mt) {
                unsigned a0 = aBase + (unsigned)((2 * clog) * 2048
                               + ((wm8 >> 4) + mt) * 128 + lm * 8);
                r0[mt] = tr16(a0);
                r1[mt] = tr16(a0 + 2048);
            }
            // ---- B-fragments ----
            bf16x8 bb[4];
#pragma unroll
            for (int nt = 0; nt < 4; ++nt) {
                int n = wn8 + nt * 16 + lm;
                bb[nt] = *(const bf16x8*)(sB + n * 128 + ((clog ^ (n & 7)) * 16));
            }
            // tr results untracked by compiler: drain + fence (rule 18)
            asm volatile("s_waitcnt lgkmcnt(0)" ::: "memory");
            __builtin_amdgcn_sched_barrier(0);
#pragma unroll
            for (int mt = 0; mt < 8; ++mt) {
                union { unsigned long long u[2]; bf16x8 v; } cv;
                cv.u[0] = r0[mt]; cv.u[1] = r1[mt];
                bf16x8 af = cv.v;
#pragma unroll
                for (int nt = 0; nt < 4; ++nt)
                    acc[mt][nt] = __builtin_amdgcn_mfma_f32_16x16x32_bf16(
                        af, bb[nt], acc[mt][nt], 0, 0, 0);
            }
        }
    }

    // ---- epilogue: bias + GLU (a,g lane-local via interleaved Wt) ----
#pragma unroll
    for (int mt = 0; mt < 8; ++mt)
#pragma unroll
        for (int hb = 0; hb < 2; ++hb) {
            int hc = (((nb + wn8) >> 5) + hb) * 16 + lm;
            float bba = bv[hc], bbg = bv[hc + 1024];
#pragma unroll
            for (int r = 0; r < 4; ++r) {
                int m = mb + wm8 + mt * 16 + q * 4 + r;
                float za = acc[mt][2 * hb][r] + bba;
                float zg = acc[mt][2 * hb + 1][r] + bbg;
                out[(size_t)m * H_ + hc] = za / (1.0f + expf(-zg));
            }
        }
}

// ---------------------------------------------------------------------------
extern "C" void kernel_launch(void* const* d_in, const int* in_sizes, int n_in,
                              void* d_out, int out_size, void* d_ws, size_t ws_size,
                              hipStream_t stream) {
    const float* x      = (const float*)d_in[0];
    const float* log_dt = (const float*)d_in[1];
    const float* Arl    = (const float*)d_in[2];
    const float* Aim    = (const float*)d_in[3];
    const float* Cr     = (const float*)d_in[4];
    const float* Ci     = (const float*)d_in[5];
    const float* Dv     = (const float*)d_in[6];
    const float* W      = (const float*)d_in[7];
    const float* bv     = (const float*)d_in[8];
    float* out = (float*)d_out;

    char* ws = (char*)d_ws;
    // layout:
    //   [0,  32M) xTb bf16
    //   [32M,64M) yTa bf16 (consumed directly by gemm_glu as A^T)
    //   [64M,88M) Bt | [88M,104M) Qt | [104M,104.5M) wT | [105M,109M) Wt
    __hip_bfloat16*  xTb = (__hip_bfloat16*)ws;
    __hip_bfloat16*  yTa = (__hip_bfloat16*)(ws + (32u << 20));
    char*            Btg = ws + (64u << 20);
    char*            Qtg = Btg + (size_t)H_ * 192 * 64 * 2;          // +24M
    float2*          wTg = (float2*)(ws + (104u << 20));
    __hip_bfloat16*  Wt  = (__hip_bfloat16*)(ws + (105u << 20));

    prep<<<2176, 256, 0, stream>>>(x, log_dt, Arl, Aim, Cr, Ci, W,
                                   xTb, (__hip_bfloat16*)Btg,
                                   (__hip_bfloat16*)Qtg, wTg, Wt);
    chunk_scan<<<4096, 256, 0, stream>>>(xTb, Btg, Qtg, wTg, Dv, yTa);
    gemm_glu<<<512, 512, 0, stream>>>(yTa, Wt, bv, out);
}

// Round 9
// 296.790 us; speedup vs baseline: 1.0504x; 1.0504x over previous
//
#include <hip/hip_runtime.h>
#include <hip/hip_bf16.h>

// Problem constants
#define B_ 16
#define L_ 1024
#define H_ 1024
#define N_ 64
// M = B*L = 16384, K = H = 1024, output cols = 2H = 2048 (a|g pairs)
// Chunked SSM: T=64 chunk, 16 chunks/seq.

typedef __bf16 bf16x8 __attribute__((ext_vector_type(8)));
typedef float  f32x4  __attribute__((ext_vector_type(4)));
typedef unsigned short u16x4 __attribute__((ext_vector_type(4)));
typedef unsigned short u16x8 __attribute__((ext_vector_type(8)));

// async global->LDS, 16B per lane; LDS dest is wave-uniform base + lane*16
__device__ __forceinline__ void gll16(const void* g, void* l) {
    __builtin_amdgcn_global_load_lds(
        (const __attribute__((address_space(1))) unsigned int*)g,
        (__attribute__((address_space(3))) unsigned int*)l,
        16, 0, 0);
}

// hardware transpose-read. Semantics (HW-verified round 4):
// lane supplies the address of ITS 64-bit slot; HW forms the 128B-aligned
// window W = addr & ~127, slot i = (addr>>3)&15, and delivers the 4 bf16 at
// bytes W + i*2 + j*32 (j=0..3) — i.e. column i of the window viewed as a
// [4][16] row-major bf16 subtile. Correct usage: addr = subtile_base + lm*8.
__device__ __forceinline__ unsigned long long tr16(unsigned a) {
    unsigned long long d;
    asm volatile("ds_read_b64_tr_b16 %0, %1" : "=v"(d) : "v"(a));
    return d;
}

__device__ __forceinline__ float gelu_tanh(float yv) {
    float u = yv + 0.044715f * yv * yv * yv;
    return 0.5f * yv * (1.0f + tanhf(0.7978845608028654f * u));
}

// ---------------------------------------------------------------------------
// K0 "prep": one kernel, 2176 blocks x 256 threads.
//  [0,1024):    x [B,L,H] f32 -> xTb [B*H, L] bf16 — LDS-staged transpose:
//               coalesced 1KB row reads -> swizzled 32KB LDS tile ->
//               coalesced 128B row writes.
//  [1024,1152): W [1024,2048] f32 -> Wt [2048,1024] bf16 (same scheme)
//  [1152,2176): build_tables (Bt/Qt/wT), one h per block (sm[0..2304) only)
// ---------------------------------------------------------------------------
__global__ __launch_bounds__(256) void prep(
        const float* __restrict__ x, const float* __restrict__ log_dt,
        const float* __restrict__ Arl, const float* __restrict__ Aim,
        const float* __restrict__ Cr, const float* __restrict__ Ci,
        const float* __restrict__ W,
        __hip_bfloat16* __restrict__ xTb, __hip_bfloat16* __restrict__ Bt,
        __hip_bfloat16* __restrict__ Qt, float2* __restrict__ wT,
        __hip_bfloat16* __restrict__ Wt) {
    __shared__ char sm[32768];
    int idx = blockIdx.x, t = threadIdx.x;
    int wv = t >> 6, lane = t & 63;

    if (idx < 1152) {
        // ---- transpose (x or W): 64 rows x 256 cols f32 -> bf16 ----
        const float* src;            // input tile base (row 0, col 0)
        size_t in_stride;            // input row stride (floats)
        unsigned short* dst;         // output tile base (row 0, col 0)
        size_t out_stride;           // output row stride (elems)
        if (idx < 1024) {
            int b = idx >> 6, lt = (idx >> 2) & 15, ht = idx & 3;
            int l0 = lt * 64, hb0 = ht * 256;
            src = x + ((size_t)b * L_ + l0) * H_ + hb0;
            in_stride = H_;
            dst = (unsigned short*)xTb + ((size_t)b * H_ + hb0) * L_ + l0;
            out_stride = L_;
        } else {
            int id2 = idx - 1024;
            int kt = id2 >> 3, ntile = id2 & 7;
            int k0 = kt * 64, nb0 = ntile * 256;
            src = W + (size_t)k0 * 2048 + nb0;
            in_stride = 2048;
            dst = (unsigned short*)Wt + (size_t)nb0 * H_ + k0;
            out_stride = H_;
        }
        // phase A: row r = j*4+wv, lane covers 4 cols -> 8B swizzled LDS write
#pragma unroll
        for (int j = 0; j < 16; ++j) {
            int r = j * 4 + wv;
            float4 v = *(const float4*)(src + (size_t)r * in_stride + lane * 4);
            __hip_bfloat16 h0 = __float2bfloat16(v.x), h1 = __float2bfloat16(v.y),
                           h2 = __float2bfloat16(v.z), h3 = __float2bfloat16(v.w);
            u16x4 pk;
            pk[0] = *(unsigned short*)&h0; pk[1] = *(unsigned short*)&h1;
            pk[2] = *(unsigned short*)&h2; pk[3] = *(unsigned short*)&h3;
            *(u16x4*)(sm + r * 512 + ((lane * 8) ^ (((r >> 3) & 7) << 4))) = pk;
        }
        __syncthreads();
        // phase B: out row hh = i*32+wv*8+r8, lane's c8 picks 8-col chunk
        {
            int r8l = lane >> 3, c8l = lane & 7;
            int swz = c8l << 4;          // (r>>3)&7 == c8l for r = c8l*8+k
#pragma unroll
            for (int i = 0; i < 8; ++i) {
                int hh = i * 32 + wv * 8 + r8l;
                u16x8 o;
#pragma unroll
                for (int k = 0; k < 8; ++k) {
                    int r = c8l * 8 + k;
                    o[k] = *(unsigned short*)(sm + r * 512 + ((hh * 2) ^ swz));
                }
                *(u16x8*)(dst + (size_t)hh * out_stride + c8l * 8) = o;
            }
        }
        return;
    }
    // ---- build_tables: h = idx - 1152 ----
    {
        float* drs  = (float*)sm;            // [64]
        float* dis  = (float*)(sm + 256);    // [64]
        float* c2rs = (float*)(sm + 512);    // [64]
        float* c2is = (float*)(sm + 768);    // [64]
        float (*kp)[64] = (float(*)[64])(sm + 1024);  // [4][64]
        float* kv   = (float*)(sm + 2048);   // [64]
        int h = idx - 1152;

        if (t < 64) {
            int n = t, i = h * 64 + n;
            float dt = expf(log_dt[h]);
            float ar = -expf(Arl[i]), ai = Aim[i];
            float dr = dt * ar, di = dt * ai;
            drs[n] = dr; dis[n] = di;
            float e = expf(dr);
            float wr = e * cosf(di), wi = e * sinf(di);
            float em1r = wr - 1.0f, em1i = wi;
            float Crv = Cr[i], Civ = Ci[i];
            float tr = Crv * em1r - Civ * em1i;
            float ti = Crv * em1i + Civ * em1r;
            float inv = 1.0f / (ar * ar + ai * ai);
            c2rs[n] = 2.0f * (tr * ar + ti * ai) * inv;
            c2is[n] = 2.0f * (ti * ar - tr * ai) * inv;
            // w^64 for the chunk-scan carry
            float jf = 64.0f;
            float er64 = expf(jf * dr);
            float ph64 = jf * di;
            wT[h * 64 + n] = make_float2(er64 * cosf(ph64), er64 * sinf(ph64));
        }
        __syncthreads();
        // kv[j] = sum_n c2r*Re(w^j) - c2i*Im(w^j), partial sums per 16-n part
        {
            int j = t & 63, part = t >> 6;
            float jf = (float)j;
            float s = 0.0f;
            for (int nn = part * 16; nn < part * 16 + 16; ++nn) {
                float er = expf(jf * drs[nn]);
                float ph = jf * dis[nn];
                float wr = er * cosf(ph), wi = er * sinf(ph);
                s += c2rs[nn] * wr - c2is[nn] * wi;
            }
            kp[part][j] = s;
        }
        __syncthreads();
        if (t < 64) kv[t] = kp[0][t] + kp[1][t] + kp[2][t] + kp[3][t];
        __syncthreads();
        // Bt rows 0..63: causal lower-triangular kernel
#pragma unroll
        for (int it = 0; it < 16; ++it) {
            int id3 = it * 256 + t, row = id3 >> 6, col = id3 & 63;
            int d = row - col;
            float v = (d >= 0) ? kv[d] : 0.0f;
            Bt[(size_t)(h * 192 + row) * 64 + col] = __float2bfloat16(v);
        }
        // Bt rows 64..191: w^(63-j) powers, rows 64+2n (Re) / 64+2n+1 (Im)
#pragma unroll
        for (int it = 0; it < 16; ++it) {
            int id3 = it * 256 + t;
            int n = id3 >> 6, j = id3 & 63;
            float jf = (float)(63 - j);
            float er = expf(jf * drs[n]);
            float ph = jf * dis[n];
            float wr = er * cosf(ph), wi = er * sinf(ph);
            Bt[(size_t)(h * 192 + 64 + 2 * n) * 64 + j]     = __float2bfloat16(wr);
            Bt[(size_t)(h * 192 + 64 + 2 * n + 1) * 64 + j] = __float2bfloat16(wi);
        }
        // Qt: row trow, col pair (2n, 2n+1) = (Re, -Im) of c2 * w^(trow+1)
#pragma unroll
        for (int it = 0; it < 16; ++it) {
            int id3 = it * 256 + t;
            int trow = id3 >> 6, n = id3 & 63;
            float jf = (float)(trow + 1);
            float er = expf(jf * drs[n]);
            float ph = jf * dis[n];
            float wr = er * cosf(ph), wi = er * sinf(ph);
            float cR = c2rs[n] * wr - c2is[n] * wi;
            float cI = c2rs[n] * wi + c2is[n] * wr;
            __hip_bfloat16* qp = Qt + (size_t)(h * 64 + trow) * 128 + 2 * n;
            qp[0] = __float2bfloat16(cR);
            qp[1] = __float2bfloat16(-cI);
        }
    }
}

// ---------------------------------------------------------------------------
// K2: fused chunked SSM (M=64 rows = 4 batches, 48K LDS, 3 blocks/CU).
// ---------------------------------------------------------------------------
__global__ __launch_bounds__(256, 3) void chunk_scan(
        const __hip_bfloat16* __restrict__ xTb, const char* __restrict__ Btg,
        const char* __restrict__ Qtg, const float2* __restrict__ wTg,
        const float* __restrict__ Dv, __hip_bfloat16* __restrict__ yTa) {
    __shared__ char lds[49152];
    char* sX = lds;              // [64][128B]
    char* sB = lds + 8192;       // [192][128B]
    char* sS = lds;              // [64 rows][512B] f32, post-GEMM1 overlay
    char* sQ = lds + 32768;      // [64][256B]

    int tid = threadIdx.x, wv = tid >> 6, lane = tid & 63;
    int lm = lane & 15, q = lane >> 4, r8 = lane >> 3, c8 = lane & 7;
    // XCD-aware decode: h = (idx>>5)*8 + (idx&7); member m = (idx>>3)&3
    int idx = blockIdx.x;
    int h  = ((idx >> 5) << 3) | (idx & 7);
    int b0 = ((idx >> 3) & 3) * 4;

    int csrc = c8 ^ r8;
    // ---- stage sB: 24 wave-loads of 8 rows x 128B ----
#pragma unroll
    for (int j = 0; j < 6; ++j) {
        int i = wv * 6 + j;
        gll16(Btg + ((size_t)(h * 192 + i * 8 + r8)) * 128 + csrc * 16,
              sB + i * 1024);
    }
    // ---- stage sQ: 16 wave-loads of 4 rows x 256B ----
    {
        int r4 = lane >> 4, c16 = lane & 15;
#pragma unroll
        for (int j = 0; j < 4; ++j) {
            int i = wv * 4 + j;
            gll16(Qtg + (size_t)(h * 64 + i * 4 + r4) * 256 + (c16 ^ r4) * 16,
                  sQ + i * 1024);
        }
    }
    // ---- stage sX via gll16: 8 groups of 8 rows x 128B, 2 per wave ----
    {
        const char* xb = (const char*)xTb;
#pragma unroll
        for (int j = 0; j < 2; ++j) {
            int i = wv * 2 + j;                      // row group
            int bp = b0 + (i >> 1);                  // batch of this group
            int ch = (i & 1) * 8 + r8;               // chunk index (row&15)
            gll16(xb + ((size_t)(bp * H_ + h)) * 2048 + ch * 128 + csrc * 16,
                  sX + i * 1024);
        }
    }
    __syncthreads();

    // ---- GEMM1: wave rows wv*16+lm, N=192 (12 tiles), K=64 ----
    f32x4 acc[12];
#pragma unroll
    for (int nt = 0; nt < 12; ++nt) acc[nt] = (f32x4){0.f, 0.f, 0.f, 0.f};
#pragma unroll
    for (int kk = 0; kk < 2; ++kk) {
        int clog = kk * 4 + q;
        int m = wv * 16 + lm;
        bf16x8 af = *(const bf16x8*)(sX + m * 128 + ((clog ^ (m & 7)) * 16));
#pragma unroll
        for (int nt = 0; nt < 12; ++nt) {
            int nrow = nt * 16 + lm;
            bf16x8 bf = *(const bf16x8*)(sB + nrow * 128 + ((clog ^ (nrow & 7)) * 16));
            acc[nt] = __builtin_amdgcn_mfma_f32_16x16x32_bf16(
                af, bf, acc[nt], 0, 0, 0);
        }
    }
    __syncthreads();   // everyone done with sX/sB -> sS overlay is safe

    // ---- write Sloc (nt 4..11 -> ri 0..127) into sS f32 swizzled ----
#pragma unroll
    for (int nt = 4; nt < 12; ++nt) {
        int ri = (nt - 4) * 16 + lm;
#pragma unroll
        for (int r = 0; r < 4; ++r) {
            int row = wv * 16 + q * 4 + r;
            *(float*)(sS + row * 512 + (((ri >> 2) ^ (row & 7)) * 16)
                      + (ri & 3) * 4) = acc[nt][r];
        }
    }
    __syncthreads();

    // ---- serial chunk scan: one chain per thread (n = tid&63, bp = wv) ----
    {
        int n = tid & 63, bp = tid >> 6;
        float2 wt = wTg[h * 64 + n];             // w^64
        float sr = 0.0f, si = 0.0f;
#pragma unroll 1
        for (int c = 0; c < 16; ++c) {
            int row = bp * 16 + c;
            char* p = sS + row * 512 + (((n >> 1) ^ (row & 7)) * 16)
                      + (n & 1) * 8;
            float2 loc = *(float2*)p;
            *(float2*)p = make_float2(sr, si);   // S_in before update
            float nr2 = wt.x * sr - wt.y * si + loc.x;
            float ni2 = wt.x * si + wt.y * sr + loc.y;
            sr = nr2; si = ni2;
        }
    }
    __syncthreads();

    // ---- GEMM2: y += S_in[64 x 128] * Qt^T, K=128 (4 k-steps) ----
#pragma unroll
    for (int ks = 0; ks < 4; ++ks) {
        int row = wv * 16 + lm;
        int cf0 = ks * 8 + q * 2;
        f32x4 a0 = *(const f32x4*)(sS + row * 512 + ((cf0 ^ (row & 7)) * 16));
        f32x4 a1 = *(const f32x4*)(sS + row * 512 + (((cf0 + 1) ^ (row & 7)) * 16));
        bf16x8 af;
        af[0] = (__bf16)a0[0]; af[1] = (__bf16)a0[1];
        af[2] = (__bf16)a0[2]; af[3] = (__bf16)a0[3];
        af[4] = (__bf16)a1[0]; af[5] = (__bf16)a1[1];
        af[6] = (__bf16)a1[2]; af[7] = (__bf16)a1[3];
#pragma unroll
        for (int nt = 0; nt < 4; ++nt) {
            int trow = nt * 16 + lm;
            int clog = ks * 4 + q;
            bf16x8 bq = *(const bf16x8*)(sQ + trow * 256 + ((clog ^ (trow & 3)) * 16));
            acc[nt] = __builtin_amdgcn_mfma_f32_16x16x32_bf16(
                af, bq, acc[nt], 0, 0, 0);
        }
    }

    // ---- epilogue: D-skip (bf16 x) + GELU -> yTa ----
    float Dh = Dv[h];
#pragma unroll
    for (int nt = 0; nt < 4; ++nt)
#pragma unroll
        for (int r = 0; r < 4; ++r) {
            int row = wv * 16 + q * 4 + r;
            int seq = (b0 + (row >> 4)) * H_ + h;
            int l   = (row & 15) * 64 + nt * 16 + lm;
            float xv = __bfloat162float(xTb[(size_t)seq * L_ + l]);
            float yv = acc[nt][r] + xv * Dh;
            yTa[(size_t)seq * L_ + l] = __float2bfloat16(gelu_tanh(yv));
        }
}

// ---------------------------------------------------------------------------
// K4: Z = Y @ Wt^T (+b), fused GLU epilogue. (round-6 structure, 128x128
// tile, 4 waves, 32KB LDS, 2-barrier loop.)
// A-operand read DIRECTLY from yTa = Y^T [B*H, L] via ds_read_b64_tr_b16.
// REFINEMENT vs r6: the two kk sub-phases' LDS reads (16 tr16 + 8 B-frag
// b128) are all issued BEFORE a SINGLE lgkmcnt(0) drain per kt (was one
// drain per kk) -> half the full-LDS-pipeline drains, tr16s pipeline deeper.
// ---------------------------------------------------------------------------
__global__ __launch_bounds__(256, 3) void gemm_glu(
        const __hip_bfloat16* __restrict__ Yt, const __hip_bfloat16* __restrict__ Wt,
        const float* __restrict__ bv, float* __restrict__ out) {
    __shared__ char lds[32768];
    char* sA  = lds;             // A^T tile, subtiled, 16 KiB
    char* sBa = lds + 16384;     // [64][128B] = 8 KiB
    char* sBg = lds + 24576;     // [64][128B] = 8 KiB

    int tid = threadIdx.x, wv = tid >> 6, lane = tid & 63;
    int mb = (blockIdx.x & 127) * 128;
    int h0 = (blockIdx.x >> 7) * 64;
    int bA = mb >> 10;           // batch of this M-tile (128 | 1024)
    int l0 = mb & 1023;          // sequence-pos base
    int r8 = lane >> 3, c8 = lane & 7, csrc = c8 ^ r8;
    int wm = (wv >> 1) * 64, wn = (wv & 1) * 32;
    int lm = lane & 15, q = lane >> 4;

    // A-staging per-lane decode: issue kq -> k = kq*4 + kA, m-offset mA
    int kA = (lane >> 1) & 3;
    int mA = (lane >> 3) * 16 + (lane & 1) * 8;

    const char* Yb = (const char*)Yt;
    const char* Wb = (const char*)Wt;
    unsigned aBase = (unsigned)(size_t)sA;

    f32x4 accA[4][2], accG[4][2];
#pragma unroll
    for (int i = 0; i < 4; ++i)
#pragma unroll
        for (int j = 0; j < 2; ++j) {
            accA[i][j] = (f32x4){0.f, 0.f, 0.f, 0.f};
            accG[i][j] = (f32x4){0.f, 0.f, 0.f, 0.f};
        }

    for (int kt = 0; kt < 16; ++kt) {
        int k0b = kt * 128;      // byte offset into Wt rows
        __syncthreads();
        // ---- stage A^T: 16 issues of 1KB (4 per wave) ----
#pragma unroll
        for (int j = 0; j < 4; ++j) {
            int kq = wv * 4 + j;
            gll16(Yb + ((size_t)(bA * H_ + kt * 64 + kq * 4 + kA)) * 2048
                      + (size_t)(l0 + mA) * 2,
                  sA + kq * 1024);
        }
        // ---- stage Ba/Bg from Wt rows ----
#pragma unroll
        for (int j = 0; j < 2; ++j) {
            int i = wv * 2 + j;
            int n = h0 + i * 8 + r8;
            gll16(Wb + (size_t)n * 2048 + k0b + csrc * 16, sBa + i * 1024);
            gll16(Wb + (size_t)(n + 1024) * 2048 + k0b + csrc * 16, sBg + i * 1024);
        }
        __syncthreads();

        // ---- ALL LDS reads for this kt (both kk), then one drain ----
        unsigned long long r0[2][4], r1[2][4];
        bf16x8 ba[2][2], bg[2][2];
#pragma unroll
        for (int kk = 0; kk < 2; ++kk) {
            int clog = kk * 4 + q;
#pragma unroll
            for (int mt = 0; mt < 4; ++mt) {
                unsigned a0 = aBase + (unsigned)(clog * 2048
                               + ((wm >> 4) + mt) * 128 + lm * 8);
                r0[kk][mt] = tr16(a0);
                r1[kk][mt] = tr16(a0 + 1024);
            }
#pragma unroll
            for (int nt = 0; nt < 2; ++nt) {
                int n = wn + nt * 16 + lm;
                int cph = (clog ^ (n & 7)) * 16;
                ba[kk][nt] = *(const bf16x8*)(sBa + n * 128 + cph);
                bg[kk][nt] = *(const bf16x8*)(sBg + n * 128 + cph);
            }
        }
        // tr results untracked by the compiler: drain + fence (rule 18)
        asm volatile("s_waitcnt lgkmcnt(0)" ::: "memory");
        __builtin_amdgcn_sched_barrier(0);

#pragma unroll
        for (int kk = 0; kk < 2; ++kk)
#pragma unroll
            for (int mt = 0; mt < 4; ++mt) {
                union { unsigned long long u[2]; bf16x8 v; } cv;
                cv.u[0] = r0[kk][mt]; cv.u[1] = r1[kk][mt];
                bf16x8 af = cv.v;
#pragma unroll
                for (int nt = 0; nt < 2; ++nt) {
                    accA[mt][nt] = __builtin_amdgcn_mfma_f32_16x16x32_bf16(
                        af, ba[kk][nt], accA[mt][nt], 0, 0, 0);
                    accG[mt][nt] = __builtin_amdgcn_mfma_f32_16x16x32_bf16(
                        af, bg[kk][nt], accG[mt][nt], 0, 0, 0);
                }
            }
    }
#pragma unroll
    for (int mt = 0; mt < 4; ++mt)
#pragma unroll
        for (int nt = 0; nt < 2; ++nt) {
            int hc = h0 + wn + nt * 16 + lm;
            float bba = bv[hc], bbg = bv[hc + 1024];
#pragma unroll
            for (int r = 0; r < 4; ++r) {
                int m = mb + wm + mt * 16 + q * 4 + r;
                float za = accA[mt][nt][r] + bba;
                float zg = accG[mt][nt][r] + bbg;
                out[(size_t)m * H_ + hc] = za / (1.0f + expf(-zg));
            }
        }
}

// ---------------------------------------------------------------------------
extern "C" void kernel_launch(void* const* d_in, const int* in_sizes, int n_in,
                              void* d_out, int out_size, void* d_ws, size_t ws_size,
                              hipStream_t stream) {
    const float* x      = (const float*)d_in[0];
    const float* log_dt = (const float*)d_in[1];
    const float* Arl    = (const float*)d_in[2];
    const float* Aim    = (const float*)d_in[3];
    const float* Cr     = (const float*)d_in[4];
    const float* Ci     = (const float*)d_in[5];
    const float* Dv     = (const float*)d_in[6];
    const float* W      = (const float*)d_in[7];
    const float* bv     = (const float*)d_in[8];
    float* out = (float*)d_out;

    char* ws = (char*)d_ws;
    // layout:
    //   [0,  32M) xTb bf16
    //   [32M,64M) yTa bf16 (consumed directly by gemm_glu as A^T)
    //   [64M,88M) Bt | [88M,104M) Qt | [104M,104.5M) wT | [105M,109M) Wt
    __hip_bfloat16*  xTb = (__hip_bfloat16*)ws;
    __hip_bfloat16*  yTa = (__hip_bfloat16*)(ws + (32u << 20));
    char*            Btg = ws + (64u << 20);
    char*            Qtg = Btg + (size_t)H_ * 192 * 64 * 2;          // +24M
    float2*          wTg = (float2*)(ws + (104u << 20));
    __hip_bfloat16*  Wt  = (__hip_bfloat16*)(ws + (105u << 20));

    prep<<<2176, 256, 0, stream>>>(x, log_dt, Arl, Aim, Cr, Ci, W,
                                   xTb, (__hip_bfloat16*)Btg,
                                   (__hip_bfloat16*)Qtg, wTg, Wt);
    chunk_scan<<<4096, 256, 0, stream>>>(xTb, Btg, Qtg, wTg, Dv, yTa);
    gemm_glu<<<2048, 256, 0, stream>>>(yTa, Wt, bv, out);
}